// Round 1
// baseline (550.800 us; speedup 1.0000x reference)
//
#include <hip/hip_runtime.h>
#include <math.h>

// GaussianLayer: out[b,i,j,k] = exp(-0.5*((x-mean[k])/std[k])^2) / (sqrt(2pi)*std[k])
// input: [B=4, N=512, N=512] f32 (4 MB), means/stds: [1, K=128] f32.
// Output: [B*N*N, K] f32 = 537 MB -> pure HBM-write-bound.
//
// Mapping: 32 lanes per input element; lane owns k-quad (float4 write).
// Wave = 2 input elements = 1 KiB contiguous store. Per-k constants hoisted
// into registers before the grid-stride loop.

#define K_DIM 128
#define INV_PRE_EXP 0.3989422804014327f   // 1/sqrt(2*pi)

__global__ __launch_bounds__(256) void gaussian_layer_kernel(
    const float* __restrict__ in,
    const float* __restrict__ means,
    const float* __restrict__ stds,
    float* __restrict__ out,
    int n_elems) {

    // Each group of 32 consecutive threads covers one input element's K=128.
    const int kq = (threadIdx.x & 31) * 4;   // this lane's k quad base

    // Hoist per-k constants: mean, inv_std, coef = inv_std/sqrt(2pi)
    float4 m = *reinterpret_cast<const float4*>(means + kq);
    float4 s = *reinterpret_cast<const float4*>(stds + kq);

    const float is0 = 1.0f / (fabsf(s.x) + 0.01f);
    const float is1 = 1.0f / (fabsf(s.y) + 0.01f);
    const float is2 = 1.0f / (fabsf(s.z) + 0.01f);
    const float is3 = 1.0f / (fabsf(s.w) + 0.01f);
    const float c0 = is0 * INV_PRE_EXP;
    const float c1 = is1 * INV_PRE_EXP;
    const float c2 = is2 * INV_PRE_EXP;
    const float c3 = is3 * INV_PRE_EXP;

    int e = (int)((blockIdx.x * blockDim.x + threadIdx.x) >> 5);
    const int estride = (int)((gridDim.x * blockDim.x) >> 5);

    for (; e < n_elems; e += estride) {
        const float x = in[e];

        float z0 = (x - m.x) * is0;
        float z1 = (x - m.y) * is1;
        float z2 = (x - m.z) * is2;
        float z3 = (x - m.w) * is3;

        float4 o;
        o.x = c0 * __expf(-0.5f * z0 * z0);
        o.y = c1 * __expf(-0.5f * z1 * z1);
        o.z = c2 * __expf(-0.5f * z2 * z2);
        o.w = c3 * __expf(-0.5f * z3 * z3);

        *reinterpret_cast<float4*>(out + (size_t)e * K_DIM + kq) = o;
    }
}

extern "C" void kernel_launch(void* const* d_in, const int* in_sizes, int n_in,
                              void* d_out, int out_size, void* d_ws, size_t ws_size,
                              hipStream_t stream) {
    const float* in    = (const float*)d_in[0];
    const float* means = (const float*)d_in[1];
    const float* stds  = (const float*)d_in[2];
    float* out = (float*)d_out;

    const int n_elems = in_sizes[0];          // B*N*N = 1,048,576

    const int threads = 256;
    const int blocks = 2048;                  // grid-stride; ~64 iters/thread

    gaussian_layer_kernel<<<blocks, threads, 0, stream>>>(in, means, stds, out, n_elems);
}